// Round 2
// baseline (700.614 us; speedup 1.0000x reference)
//
#include <hip/hip_runtime.h>
#include <hip/hip_bf16.h>
#include <cstdint>

// Transformer block: LN1 -> QKV GEMM -> attention -> proj(+res) -> LN2 -> MLP(+res)
// All GEMMs bf16 MFMA 16x16x32, fp32 accumulate. Weights pre-transposed to [N,K] bf16.
// Workspace is lifetime-aliased: peak ~140 MB. fp32 residual stream lives in d_out.

typedef __bf16 bf16;
typedef bf16 bf16x8 __attribute__((ext_vector_type(8)));
typedef float f32x4 __attribute__((ext_vector_type(4)));
typedef uint32_t u32;

__device__ __forceinline__ f32x4 mfma16(bf16x8 a, bf16x8 b, f32x4 c){
  return __builtin_amdgcn_mfma_f32_16x16x32_bf16(a, b, c, 0, 0, 0);
}

// global -> LDS direct copy, 16B per lane. LDS dest must be wave-uniform base,
// lane l lands at base + l*16. LDS offset recovered by truncating flat addr
// (shared aperture is 4GB-aligned; CK uses the same lowering).
__device__ __forceinline__ void gload16(const void* g, const void* l){
  __builtin_amdgcn_global_load_lds(
      (__attribute__((address_space(1))) u32*)(uintptr_t)g,
      (__attribute__((address_space(3))) u32*)(u32)(uintptr_t)l,
      16, 0, 0);
}

// ---------------- weight transpose-cast: W[K,N] f32 -> Wt[N,K] bf16 ----------------
__global__ __launch_bounds__(256)
void transpose_cast(const float* __restrict__ W, bf16* __restrict__ Wt, int K, int N)
{
  __shared__ float t[64][65];
  int n0 = blockIdx.x * 64, k0 = blockIdx.y * 64;
  int tid = threadIdx.x;
  int c = tid & 63, r4 = tid >> 6;
#pragma unroll
  for (int i = 0; i < 16; ++i){
    int r = r4 * 16 + i;
    t[r][c] = W[(size_t)(k0 + r) * N + n0 + c];
  }
  __syncthreads();
#pragma unroll
  for (int i = 0; i < 16; ++i){
    int r = r4 * 16 + i;
    Wt[(size_t)(n0 + r) * K + k0 + c] = (bf16)t[c][r];
  }
}

// ---------------- LayerNorm: f32 [rows,768] -> bf16, one block per row ----------------
__global__ __launch_bounds__(256)
void ln_kernel(const float* __restrict__ x, const float* __restrict__ g,
               const float* __restrict__ b, bf16* __restrict__ out)
{
  int row = blockIdx.x;
  int tid = threadIdx.x;
  const float* xr = x + (size_t)row * 768;
  float v0 = xr[tid], v1 = xr[tid + 256], v2 = xr[tid + 512];
  float s = v0 + v1 + v2;
  float ss = v0*v0 + v1*v1 + v2*v2;
#pragma unroll
  for (int m = 1; m < 64; m <<= 1){
    s  += __shfl_xor(s,  m, 64);
    ss += __shfl_xor(ss, m, 64);
  }
  __shared__ float red[8];
  int w = tid >> 6, l = tid & 63;
  if (l == 0){ red[w] = s; red[4 + w] = ss; }
  __syncthreads();
  s  = red[0] + red[1] + red[2] + red[3];
  ss = red[4] + red[5] + red[6] + red[7];
  float mu  = s * (1.0f / 768.0f);
  float var = ss * (1.0f / 768.0f) - mu * mu;
  float rs  = rsqrtf(var + 1e-5f);
  bf16* o = out + (size_t)row * 768;
  o[tid]       = (bf16)((v0 - mu) * rs * g[tid]       + b[tid]);
  o[tid + 256] = (bf16)((v1 - mu) * rs * g[tid + 256] + b[tid + 256]);
  o[tid + 512] = (bf16)((v2 - mu) * rs * g[tid + 512] + b[tid + 512]);
}

// ---------------- GEMM: C[M,N] = A[M,K](bf16) * Bt[N,K](bf16)^T ----------------
// 128x128 tile, 4 waves (2x2 of 64x64), BK=32. EPI: 0 = bf16 store,
// 1 = bf16 gelu(x+bias), 2 = f32 x+bias+res.
template<int EPI>
__global__ __launch_bounds__(256)
void gemm128(const bf16* __restrict__ A, const bf16* __restrict__ Bt,
             const float* __restrict__ bias, const float* __restrict__ res,
             void* __restrict__ Cout, int M, int N, int K)
{
  __shared__ bf16 Al[128 * 32];
  __shared__ bf16 Bl[128 * 32];
  int nbn = N >> 7;
  int nwg = gridDim.x;
  int cpx = nwg >> 3;                      // all grids are %8==0 -> bijective
  int bid = (int)blockIdx.x;
  int sw  = (bid & 7) * cpx + (bid >> 3);  // XCD-aware swizzle
  int bm = sw / nbn, bn = sw % nbn;
  int tid = threadIdx.x;
  int w = tid >> 6, l = tid & 63;
  int wr = w >> 1, wc = w & 1;
  int lr = l & 15, lg = l >> 4;
  size_t rowA = (size_t)bm * 128, colB = (size_t)bn * 128;

  f32x4 acc[4][4];
#pragma unroll
  for (int m = 0; m < 4; ++m)
#pragma unroll
    for (int n = 0; n < 4; ++n) acc[m][n] = f32x4{0.f, 0.f, 0.f, 0.f};

  int rsub = l >> 2;          // 0..15: row within 16-row segment
  int ksub = (l & 3) * 8;     // 0,8,16,24: k offset

  for (int kt = 0; kt < K; kt += 32){
    __syncthreads();
#pragma unroll
    for (int i = 0; i < 2; ++i){
      int sg = w * 2 + i;     // 8 segments of 16 rows
      gload16(A  + (rowA + sg * 16 + rsub) * K + kt + ksub, &Al[sg * 512]);
      gload16(Bt + (colB + sg * 16 + rsub) * K + kt + ksub, &Bl[sg * 512]);
    }
    __syncthreads();
    bf16x8 af[4], bfr[4];
#pragma unroll
    for (int m = 0; m < 4; ++m)
      af[m]  = *(const bf16x8*)&Al[(wr * 64 + m * 16 + lr) * 32 + lg * 8];
#pragma unroll
    for (int n = 0; n < 4; ++n)
      bfr[n] = *(const bf16x8*)&Bl[(wc * 64 + n * 16 + lr) * 32 + lg * 8];
#pragma unroll
    for (int m = 0; m < 4; ++m)
#pragma unroll
      for (int n = 0; n < 4; ++n)
        acc[m][n] = mfma16(af[m], bfr[n], acc[m][n]);
  }

  size_t crow = rowA + wr * 64;
  size_t ccol = colB + wc * 64;
#pragma unroll
  for (int m = 0; m < 4; ++m){
#pragma unroll
    for (int n = 0; n < 4; ++n){
      size_t r0 = crow + m * 16 + lg * 4;
      size_t c  = ccol + n * 16 + lr;
#pragma unroll
      for (int i = 0; i < 4; ++i){
        size_t r = r0 + i;
        float v = acc[m][n][i];
        if (EPI == 0){
          ((bf16*)Cout)[r * (size_t)N + c] = (bf16)v;
        } else if (EPI == 1){
          v += bias[c];
          v = 0.5f * v * (1.0f + erff(v * 0.70710678118654752f));
          ((bf16*)Cout)[r * (size_t)N + c] = (bf16)v;
        } else {
          v += bias[c] + res[r * (size_t)N + c];
          ((float*)Cout)[r * (size_t)N + c] = v;
        }
      }
    }
  }
}

// ---------------- Flash attention: qkv bf16 [16384,2304] -> y bf16 [16384,768] ----------------
// grid = 384 (b*s*h) * 8 q-tiles. Block: 4 waves, each wave 16 q rows.
// K/V chunks of 64 tokens staged in LDS (XOR-swizzled 16B granules).
__global__ __launch_bounds__(256)
void attn_kernel(const bf16* __restrict__ qkv, bf16* __restrict__ y)
{
  int bid = blockIdx.x;
  int qt  = bid & 7;
  int bsh = bid >> 3;
  int h = bsh % 12;
  int R = bsh / 12;
  size_t rowbase = (size_t)R * 512;
  int tid = threadIdx.x, w = tid >> 6, l = tid & 63;
  int lr = l & 15, lg = l >> 4;

  __shared__ bf16 Kl[64 * 64];        // [tok][d], swizzled
  __shared__ bf16 Vt[64 * 64];        // [d][tok], swizzled
  __shared__ bf16 Pl[4][16 * 64];     // per-wave P [q][tok], swizzled

  int q0 = qt * 64 + w * 16;
  bf16x8 qf[2];
#pragma unroll
  for (int ks = 0; ks < 2; ++ks)
    qf[ks] = *(const bf16x8*)&qkv[(rowbase + q0 + lr) * 2304 + h * 64 + ks * 32 + lg * 8];

  float mi[4], li[4];
  f32x4 oa[4];
#pragma unroll
  for (int i = 0; i < 4; ++i){ mi[i] = -1e30f; li[i] = 0.f; }
#pragma unroll
  for (int dt = 0; dt < 4; ++dt) oa[dt] = f32x4{0.f, 0.f, 0.f, 0.f};

  for (int c = 0; c < 8; ++c){
    __syncthreads();
    size_t tokbase = rowbase + c * 64;
#pragma unroll
    for (int it = 0; it < 2; ++it){
      int idx = it * 256 + tid;          // 0..511
      int t  = idx >> 3;                  // token 0..63
      int c8 = idx & 7;                   // 16B granule in d
      bf16x8 kv = *(const bf16x8*)&qkv[(tokbase + t) * 2304 + 768 + h * 64 + c8 * 8];
      *(bf16x8*)&Kl[t * 64 + ((c8 ^ (t & 7)) * 8)] = kv;
      bf16x8 vv = *(const bf16x8*)&qkv[(tokbase + t) * 2304 + 1536 + h * 64 + c8 * 8];
#pragma unroll
      for (int j = 0; j < 8; ++j){
        int d = c8 * 8 + j;
        Vt[d * 64 + (((t >> 3) ^ (d & 7)) * 8) + (t & 7)] = vv[j];
      }
    }
    __syncthreads();

    // S = Q K^T * scale
    f32x4 s[4];
#pragma unroll
    for (int tt = 0; tt < 4; ++tt){
      f32x4 a = f32x4{0.f, 0.f, 0.f, 0.f};
#pragma unroll
      for (int ks = 0; ks < 2; ++ks){
        int row = tt * 16 + lr;
        int c8 = ks * 4 + lg;
        bf16x8 kf = *(const bf16x8*)&Kl[row * 64 + ((c8 ^ (row & 7)) * 8)];
        a = mfma16(qf[ks], kf, a);
      }
      s[tt] = a * 0.125f;   // SCALE = 1/sqrt(64)
    }

    // online softmax (rows spread over lr lanes; reduce within 16-lane groups)
    float pr[4][4];
#pragma unroll
    for (int i = 0; i < 4; ++i){
      float rm = fmaxf(fmaxf(s[0][i], s[1][i]), fmaxf(s[2][i], s[3][i]));
#pragma unroll
      for (int mm = 1; mm < 16; mm <<= 1) rm = fmaxf(rm, __shfl_xor(rm, mm, 64));
      float mn = fmaxf(mi[i], rm);
      float corr = __expf(mi[i] - mn);
      float rs = 0.f;
#pragma unroll
      for (int tt = 0; tt < 4; ++tt){
        float p = __expf(s[tt][i] - mn);
        pr[tt][i] = p;
        rs += p;
      }
#pragma unroll
      for (int mm = 1; mm < 16; mm <<= 1) rs += __shfl_xor(rs, mm, 64);
      li[i] = li[i] * corr + rs;
#pragma unroll
      for (int dt = 0; dt < 4; ++dt) oa[dt][i] *= corr;
      mi[i] = mn;
    }

    // P -> LDS (bf16) to re-fragment for PV
#pragma unroll
    for (int i = 0; i < 4; ++i){
      int qr = lg * 4 + i;
#pragma unroll
      for (int tt = 0; tt < 4; ++tt){
        int tok = tt * 16 + lr;
        Pl[w][qr * 64 + (((tok >> 3) ^ (qr & 7)) * 8) + (tok & 7)] = (bf16)pr[tt][i];
      }
    }
    __syncthreads();

    // O += P V
#pragma unroll
    for (int ks = 0; ks < 2; ++ks){
      bf16x8 pf = *(const bf16x8*)&Pl[w][lr * 64 + (((ks * 4 + lg) ^ (lr & 7)) * 8)];
#pragma unroll
      for (int dt = 0; dt < 4; ++dt){
        int row = dt * 16 + lr;
        int c8 = ks * 4 + lg;
        bf16x8 vf = *(const bf16x8*)&Vt[row * 64 + ((c8 ^ (row & 7)) * 8)];
        oa[dt] = mfma16(pf, vf, oa[dt]);
      }
    }
  }

  // epilogue: O / l
#pragma unroll
  for (int i = 0; i < 4; ++i){
    float inv = 1.0f / li[i];
    size_t r = rowbase + q0 + lg * 4 + i;
#pragma unroll
    for (int dt = 0; dt < 4; ++dt)
      y[r * 768 + h * 64 + dt * 16 + lr] = (bf16)(oa[dt][i] * inv);
  }
}

// ---------------- launcher ----------------
extern "C" void kernel_launch(void* const* d_in, const int* in_sizes, int n_in,
                              void* d_out, int out_size, void* d_ws, size_t ws_size,
                              hipStream_t stream)
{
  (void)in_sizes; (void)n_in; (void)out_size; (void)ws_size;
  const float* x    = (const float*)d_in[0];
  const float* g1   = (const float*)d_in[1];
  const float* b1   = (const float*)d_in[2];
  const float* Wqkv = (const float*)d_in[3];
  const float* Wp   = (const float*)d_in[4];
  const float* bp   = (const float*)d_in[5];
  const float* g2   = (const float*)d_in[6];
  const float* b2   = (const float*)d_in[7];
  const float* W1   = (const float*)d_in[8];
  const float* bm1  = (const float*)d_in[9];
  const float* W2   = (const float*)d_in[10];
  const float* bm2  = (const float*)d_in[11];
  float* out = (float*)d_out;

  // ---- lifetime-aliased workspace layout (~140 MB peak) ----
  char* ws = (char*)d_ws;
  size_t off = 0;
  auto alloc = [&](size_t nbytes) -> void* {
    void* p = ws + off;
    off += (nbytes + 255) & ~(size_t)255;
    return p;
  };
  bf16* WqkvT = (bf16*)alloc((size_t)2304 * 768 * 2);   //  3.5 MB, persistent
  bf16* WpT   = (bf16*)alloc((size_t)768 * 768 * 2);    //  1.2 MB, persistent
  bf16* W1T   = (bf16*)alloc((size_t)3072 * 768 * 2);   //  4.7 MB, persistent
  bf16* W2T   = (bf16*)alloc((size_t)768 * 3072 * 2);   //  4.7 MB, persistent
  // region R1: h (LN1 out) -> yb (attn out) -> h2 (LN2 out); lifetimes disjoint
  char* R1 = (char*)alloc((size_t)16384 * 768 * 2);     // 25.2 MB
  // region R2: qkv -> m1; qkv dead after attention, m1 written after
  char* R2 = (char*)alloc((size_t)16384 * 3072 * 2);    // 100.7 MB (covers qkv's 75.5)
  bf16* h   = (bf16*)R1;
  bf16* yb  = (bf16*)R1;
  bf16* h2  = (bf16*)R1;
  bf16* qkv = (bf16*)R2;
  bf16* m1  = (bf16*)R2;
  float* x2 = out;   // fp32 residual stream lives in d_out (fully overwritten by proj)

  // weight transpose-casts: W[K,N] -> Wt[N,K] bf16
  transpose_cast<<<dim3(36, 12), dim3(256), 0, stream>>>(Wqkv, WqkvT, 768, 2304);
  transpose_cast<<<dim3(12, 12), dim3(256), 0, stream>>>(Wp,   WpT,   768, 768);
  transpose_cast<<<dim3(48, 12), dim3(256), 0, stream>>>(W1,   W1T,   768, 3072);
  transpose_cast<<<dim3(12, 48), dim3(256), 0, stream>>>(W2,   W2T,   3072, 768);

  // LN1: x -> h (bf16)
  ln_kernel<<<dim3(16384), dim3(256), 0, stream>>>(x, g1, b1, h);
  // QKV: h @ WqkvT^T -> qkv (bf16)
  gemm128<0><<<dim3(2304), dim3(256), 0, stream>>>(h, WqkvT, nullptr, nullptr,
                                                   (void*)qkv, 16384, 2304, 768);
  // attention: qkv -> yb (bf16)   [yb aliases h; h dead]
  attn_kernel<<<dim3(3072), dim3(256), 0, stream>>>(qkv, yb);
  // proj + bias + residual(x) -> x2 (f32, in d_out)
  gemm128<2><<<dim3(768), dim3(256), 0, stream>>>(yb, WpT, bp, x,
                                                  (void*)x2, 16384, 768, 768);
  // LN2: x2 -> h2 (bf16)   [h2 aliases yb; yb dead]
  ln_kernel<<<dim3(16384), dim3(256), 0, stream>>>(x2, g2, b2, h2);
  // MLP1 + bias + exact gelu -> m1 (bf16)   [m1 aliases qkv; qkv dead]
  gemm128<1><<<dim3(3072), dim3(256), 0, stream>>>(h2, W1T, bm1, nullptr,
                                                   (void*)m1, 16384, 3072, 768);
  // MLP2 + bias + residual(x2) -> out (f32; same-thread RMW on d_out, safe)
  gemm128<2><<<dim3(768), dim3(256), 0, stream>>>(m1, W2T, bm2, x2,
                                                  (void*)out, 16384, 768, 3072);
}

// Round 3
// 658.643 us; speedup vs baseline: 1.0637x; 1.0637x over previous
//
#include <hip/hip_runtime.h>
#include <hip/hip_bf16.h>
#include <cstdint>

// Transformer block: LN1 -> QKV GEMM -> attention -> proj(+res) -> LN2 -> MLP(+res)
// GEMM: 256x256 tile, BK=64, 8 waves, 2 LDS buffers (128KB), 4 phases/K-tile,
// counted vmcnt(4) pipeline, XOR-swizzled LDS, setprio around MFMA.

typedef __bf16 bf16;
typedef bf16 bf16x8 __attribute__((ext_vector_type(8)));
typedef float f32x4 __attribute__((ext_vector_type(4)));
typedef uint32_t u32;

__device__ __forceinline__ f32x4 mfma16(bf16x8 a, bf16x8 b, f32x4 c){
  return __builtin_amdgcn_mfma_f32_16x16x32_bf16(a, b, c, 0, 0, 0);
}

// global -> LDS direct copy, 16B per lane; LDS dest wave-uniform base + lane*16.
__device__ __forceinline__ void gload16(const void* g, const void* l){
  __builtin_amdgcn_global_load_lds(
      (__attribute__((address_space(1))) u32*)(uintptr_t)g,
      (__attribute__((address_space(3))) u32*)(u32)(uintptr_t)l,
      16, 0, 0);
}

// ---------------- weight transpose-cast: W[K,N] f32 -> Wt[N,K] bf16 ----------------
__global__ __launch_bounds__(256)
void transpose_cast(const float* __restrict__ W, bf16* __restrict__ Wt, int K, int N)
{
  __shared__ float t[64][65];
  int n0 = blockIdx.x * 64, k0 = blockIdx.y * 64;
  int tid = threadIdx.x;
  int c = tid & 63, r4 = tid >> 6;
#pragma unroll
  for (int i = 0; i < 16; ++i){
    int r = r4 * 16 + i;
    t[r][c] = W[(size_t)(k0 + r) * N + n0 + c];
  }
  __syncthreads();
#pragma unroll
  for (int i = 0; i < 16; ++i){
    int r = r4 * 16 + i;
    Wt[(size_t)(n0 + r) * K + k0 + c] = (bf16)t[c][r];
  }
}

// ---------------- LayerNorm: f32 [rows,768] -> bf16, one block per row ----------------
__global__ __launch_bounds__(256)
void ln_kernel(const float* __restrict__ x, const float* __restrict__ g,
               const float* __restrict__ b, bf16* __restrict__ out)
{
  int row = blockIdx.x;
  int tid = threadIdx.x;
  const float* xr = x + (size_t)row * 768;
  float v0 = xr[tid], v1 = xr[tid + 256], v2 = xr[tid + 512];
  float s = v0 + v1 + v2;
  float ss = v0*v0 + v1*v1 + v2*v2;
#pragma unroll
  for (int m = 1; m < 64; m <<= 1){
    s  += __shfl_xor(s,  m, 64);
    ss += __shfl_xor(ss, m, 64);
  }
  __shared__ float red[8];
  int w = tid >> 6, l = tid & 63;
  if (l == 0){ red[w] = s; red[4 + w] = ss; }
  __syncthreads();
  s  = red[0] + red[1] + red[2] + red[3];
  ss = red[4] + red[5] + red[6] + red[7];
  float mu  = s * (1.0f / 768.0f);
  float var = ss * (1.0f / 768.0f) - mu * mu;
  float rs  = rsqrtf(var + 1e-5f);
  bf16* o = out + (size_t)row * 768;
  o[tid]       = (bf16)((v0 - mu) * rs * g[tid]       + b[tid]);
  o[tid + 256] = (bf16)((v1 - mu) * rs * g[tid + 256] + b[tid + 256]);
  o[tid + 512] = (bf16)((v2 - mu) * rs * g[tid + 512] + b[tid + 512]);
}

// ---------------- GEMM 256x256: C[M,N] = A[M,K](bf16) * Bt[N,K](bf16)^T ----------------
// 8 waves (2 Mx4 N), per-wave 128x64 output, BK=64, 2 LDS buffers of (A 32KB + B 32KB).
// Per phase: 12 ds_read_b128 (swizzled) | stage 2 wave-instrs of next tile | vmcnt(4) |
// barrier | setprio1 | 16 MFMA | setprio0 | barrier.
// EPI: 0 = bf16 store, 1 = bf16 gelu(x+bias), 2 = f32 x+bias+res.
template<int EPI>
__global__ __launch_bounds__(512, 2)
void gemm256(const bf16* __restrict__ A, const bf16* __restrict__ Bt,
             const float* __restrict__ bias, const float* __restrict__ res,
             void* __restrict__ Cout, int M, int N, int K)
{
  extern __shared__ bf16 lds[];   // [2][ A:16384 | B:16384 ] elems = 128 KiB
  const int tid = threadIdx.x;
  const int w = tid >> 6, l = tid & 63;
  const int lr = l & 15, lg = l >> 4;
  const int wr = w >> 2, wc = w & 3;           // 2 x 4 wave grid
  const int nbm = M >> 8, nbn = N >> 8;
  const int nwg = nbm * nbn;
  const int cpx = nwg >> 3;                    // grids are %8==0 -> bijective
  const int bid = (int)blockIdx.x;
  const int sw  = (bid & 7) * cpx + (bid >> 3);
  const int bm = sw % nbm, bn = sw / nbm;
  const int rowA0 = bm << 8, colB0 = bn << 8;

  f32x4 acc[8][4];
#pragma unroll
  for (int i = 0; i < 8; ++i)
#pragma unroll
    for (int j = 0; j < 4; ++j) acc[i][j] = f32x4{0.f, 0.f, 0.f, 0.f};

  // staging: linear LDS dest, inverse-swizzled global source.
  // granule g' at (row, g'): holds global k-granule g = g' ^ (row&7).
  const int srow = l >> 3;              // lane's row-within-8
  const int sg   = (l & 7) ^ srow;      // source k-granule
  auto stA = [&](int T, int q){
    bf16* dst = lds + (size_t)(T & 1) * 32768 + q * 4096 + w * 512;
    int row = q * 64 + w * 8 + srow;
    gload16(A + (size_t)(rowA0 + row) * K + T * 64 + sg * 8, dst);
  };
  auto stB = [&](int T, int nh, int j){
    int hh = j * 8 + w;
    int row0 = (hh >> 2) * 64 + nh * 32 + (hh & 3) * 8;
    bf16* dst = lds + (size_t)(T & 1) * 32768 + 16384 + row0 * 64;
    int row = row0 + srow;
    gload16(Bt + (size_t)(colB0 + row) * K + T * 64 + sg * 8, dst);
  };

  const int NT = K >> 6;

  // prologue: stage tile 0 in consumption order, wait first half, barrier
  stA(0,0); stA(0,2); stB(0,0,0); stB(0,0,1);
  stA(0,1); stA(0,3); stB(0,1,0); stB(0,1,1);
  asm volatile("s_waitcnt vmcnt(4)" ::: "memory");
  __builtin_amdgcn_s_barrier();

#define PHASE(MH, NH, STAGE_STMT)                                              \
  {                                                                            \
    bf16x8 af[4][2], bfr[2][2];                                                \
    _Pragma("unroll")                                                          \
    for (int fr = 0; fr < 4; ++fr)                                             \
      _Pragma("unroll")                                                        \
      for (int kk = 0; kk < 2; ++kk){                                          \
        int row = wr * 128 + (MH) * 64 + fr * 16 + lr;                         \
        af[fr][kk] = *(const bf16x8*)&Abuf[row * 64 +                          \
                       (((kk * 4 + lg) ^ (lr & 7)) << 3)];                     \
      }                                                                        \
    _Pragma("unroll")                                                          \
    for (int fc = 0; fc < 2; ++fc)                                             \
      _Pragma("unroll")                                                        \
      for (int kk = 0; kk < 2; ++kk){                                          \
        int row = wc * 64 + (NH) * 32 + fc * 16 + lr;                          \
        bfr[fc][kk] = *(const bf16x8*)&Bbuf[row * 64 +                         \
                       (((kk * 4 + lg) ^ (lr & 7)) << 3)];                     \
      }                                                                        \
    STAGE_STMT;                                                                \
    if (more) asm volatile("s_waitcnt vmcnt(4)" ::: "memory");                 \
    else      asm volatile("s_waitcnt vmcnt(0)" ::: "memory");                 \
    __builtin_amdgcn_s_barrier();                                              \
    __builtin_amdgcn_s_setprio(1);                                             \
    _Pragma("unroll")                                                          \
    for (int fr = 0; fr < 4; ++fr)                                             \
      _Pragma("unroll")                                                        \
      for (int fc = 0; fc < 2; ++fc)                                           \
        _Pragma("unroll")                                                      \
        for (int kk = 0; kk < 2; ++kk)                                         \
          acc[(MH) * 4 + fr][(NH) * 2 + fc] =                                  \
              mfma16(af[fr][kk], bfr[fc][kk], acc[(MH) * 4 + fr][(NH) * 2 + fc]); \
    __builtin_amdgcn_s_setprio(0);                                             \
    __builtin_amdgcn_s_barrier();                                              \
  }

  for (int T = 0; T < NT; ++T){
    const bf16* Abuf = lds + (size_t)(T & 1) * 32768;
    const bf16* Bbuf = Abuf + 16384;
    const bool more = (T + 1 < NT);
    PHASE(0, 0, if (more){ stA(T+1,0); stA(T+1,2); })
    PHASE(1, 0, if (more){ stB(T+1,0,0); stB(T+1,0,1); })
    PHASE(0, 1, if (more){ stA(T+1,1); stA(T+1,3); })
    PHASE(1, 1, if (more){ stB(T+1,1,0); stB(T+1,1,1); })
  }
#undef PHASE

  // epilogue: frag (mi,ni) -> rows (mi>>2)*64+(mi&3)*16, cols (ni>>1)*32+(ni&1)*16
  const size_t crow = (size_t)rowA0 + wr * 128;
  const size_t ccol = (size_t)colB0 + wc * 64;
#pragma unroll
  for (int mi = 0; mi < 8; ++mi){
#pragma unroll
    for (int ni = 0; ni < 4; ++ni){
      size_t r0 = crow + (mi >> 2) * 64 + (mi & 3) * 16 + lg * 4;
      size_t c  = ccol + (ni >> 1) * 32 + (ni & 1) * 16 + lr;
#pragma unroll
      for (int i = 0; i < 4; ++i){
        size_t r = r0 + i;
        float v = acc[mi][ni][i];
        if (EPI == 0){
          ((bf16*)Cout)[r * (size_t)N + c] = (bf16)v;
        } else if (EPI == 1){
          v += bias[c];
          v = 0.5f * v * (1.0f + erff(v * 0.70710678118654752f));
          ((bf16*)Cout)[r * (size_t)N + c] = (bf16)v;
        } else {
          v += bias[c] + res[r * (size_t)N + c];
          ((float*)Cout)[r * (size_t)N + c] = v;
        }
      }
    }
  }
}

// ---------------- Flash attention: qkv bf16 [16384,2304] -> y bf16 [16384,768] ----------------
__global__ __launch_bounds__(256)
void attn_kernel(const bf16* __restrict__ qkv, bf16* __restrict__ y)
{
  int bid = blockIdx.x;
  int qt  = bid & 7;
  int bsh = bid >> 3;
  int h = bsh % 12;
  int R = bsh / 12;
  size_t rowbase = (size_t)R * 512;
  int tid = threadIdx.x, w = tid >> 6, l = tid & 63;
  int lr = l & 15, lg = l >> 4;

  __shared__ bf16 Kl[64 * 64];
  __shared__ bf16 Vt[64 * 64];
  __shared__ bf16 Pl[4][16 * 64];

  int q0 = qt * 64 + w * 16;
  bf16x8 qf[2];
#pragma unroll
  for (int ks = 0; ks < 2; ++ks)
    qf[ks] = *(const bf16x8*)&qkv[(rowbase + q0 + lr) * 2304 + h * 64 + ks * 32 + lg * 8];

  float mi[4], li[4];
  f32x4 oa[4];
#pragma unroll
  for (int i = 0; i < 4; ++i){ mi[i] = -1e30f; li[i] = 0.f; }
#pragma unroll
  for (int dt = 0; dt < 4; ++dt) oa[dt] = f32x4{0.f, 0.f, 0.f, 0.f};

  for (int c = 0; c < 8; ++c){
    __syncthreads();
    size_t tokbase = rowbase + c * 64;
#pragma unroll
    for (int it = 0; it < 2; ++it){
      int idx = it * 256 + tid;
      int t  = idx >> 3;
      int c8 = idx & 7;
      bf16x8 kv = *(const bf16x8*)&qkv[(tokbase + t) * 2304 + 768 + h * 64 + c8 * 8];
      *(bf16x8*)&Kl[t * 64 + ((c8 ^ (t & 7)) * 8)] = kv;
      bf16x8 vv = *(const bf16x8*)&qkv[(tokbase + t) * 2304 + 1536 + h * 64 + c8 * 8];
#pragma unroll
      for (int j = 0; j < 8; ++j){
        int d = c8 * 8 + j;
        Vt[d * 64 + (((t >> 3) ^ (d & 7)) * 8) + (t & 7)] = vv[j];
      }
    }
    __syncthreads();

    f32x4 s[4];
#pragma unroll
    for (int tt = 0; tt < 4; ++tt){
      f32x4 a = f32x4{0.f, 0.f, 0.f, 0.f};
#pragma unroll
      for (int ks = 0; ks < 2; ++ks){
        int row = tt * 16 + lr;
        int c8 = ks * 4 + lg;
        bf16x8 kf = *(const bf16x8*)&Kl[row * 64 + ((c8 ^ (row & 7)) * 8)];
        a = mfma16(qf[ks], kf, a);
      }
      s[tt] = a * 0.125f;
    }

    float pr[4][4];
#pragma unroll
    for (int i = 0; i < 4; ++i){
      float rm = fmaxf(fmaxf(s[0][i], s[1][i]), fmaxf(s[2][i], s[3][i]));
#pragma unroll
      for (int mm = 1; mm < 16; mm <<= 1) rm = fmaxf(rm, __shfl_xor(rm, mm, 64));
      float mn = fmaxf(mi[i], rm);
      float corr = __expf(mi[i] - mn);
      float rs = 0.f;
#pragma unroll
      for (int tt = 0; tt < 4; ++tt){
        float p = __expf(s[tt][i] - mn);
        pr[tt][i] = p;
        rs += p;
      }
#pragma unroll
      for (int mm = 1; mm < 16; mm <<= 1) rs += __shfl_xor(rs, mm, 64);
      li[i] = li[i] * corr + rs;
#pragma unroll
      for (int dt = 0; dt < 4; ++dt) oa[dt][i] *= corr;
      mi[i] = mn;
    }

#pragma unroll
    for (int i = 0; i < 4; ++i){
      int qr = lg * 4 + i;
#pragma unroll
      for (int tt = 0; tt < 4; ++tt){
        int tok = tt * 16 + lr;
        Pl[w][qr * 64 + (((tok >> 3) ^ (qr & 7)) * 8) + (tok & 7)] = (bf16)pr[tt][i];
      }
    }
    __syncthreads();

#pragma unroll
    for (int ks = 0; ks < 2; ++ks){
      bf16x8 pf = *(const bf16x8*)&Pl[w][lr * 64 + (((ks * 4 + lg) ^ (lr & 7)) * 8)];
#pragma unroll
      for (int dt = 0; dt < 4; ++dt){
        int row = dt * 16 + lr;
        int c8 = ks * 4 + lg;
        bf16x8 vf = *(const bf16x8*)&Vt[row * 64 + ((c8 ^ (row & 7)) * 8)];
        oa[dt] = mfma16(pf, vf, oa[dt]);
      }
    }
  }

#pragma unroll
  for (int i = 0; i < 4; ++i){
    float inv = 1.0f / li[i];
    size_t r = rowbase + q0 + lg * 4 + i;
#pragma unroll
    for (int dt = 0; dt < 4; ++dt)
      y[r * 768 + h * 64 + dt * 16 + lr] = (bf16)(oa[dt][i] * inv);
  }
}

// ---------------- launcher ----------------
extern "C" void kernel_launch(void* const* d_in, const int* in_sizes, int n_in,
                              void* d_out, int out_size, void* d_ws, size_t ws_size,
                              hipStream_t stream)
{
  (void)in_sizes; (void)n_in; (void)out_size; (void)ws_size;
  const float* x    = (const float*)d_in[0];
  const float* g1   = (const float*)d_in[1];
  const float* b1   = (const float*)d_in[2];
  const float* Wqkv = (const float*)d_in[3];
  const float* Wp   = (const float*)d_in[4];
  const float* bp   = (const float*)d_in[5];
  const float* g2   = (const float*)d_in[6];
  const float* b2   = (const float*)d_in[7];
  const float* W1   = (const float*)d_in[8];
  const float* bm1  = (const float*)d_in[9];
  const float* W2   = (const float*)d_in[10];
  const float* bm2  = (const float*)d_in[11];
  float* out = (float*)d_out;

  // allow 128KB dynamic LDS for gemm256 (idempotent, capture-safe)
  hipFuncSetAttribute((const void*)gemm256<0>, hipFuncAttributeMaxDynamicSharedMemorySize, 131072);
  hipFuncSetAttribute((const void*)gemm256<1>, hipFuncAttributeMaxDynamicSharedMemorySize, 131072);
  hipFuncSetAttribute((const void*)gemm256<2>, hipFuncAttributeMaxDynamicSharedMemorySize, 131072);

  // ---- lifetime-aliased workspace layout (~140 MB peak) ----
  char* ws = (char*)d_ws;
  size_t off = 0;
  auto alloc = [&](size_t nbytes) -> void* {
    void* p = ws + off;
    off += (nbytes + 255) & ~(size_t)255;
    return p;
  };
  bf16* WqkvT = (bf16*)alloc((size_t)2304 * 768 * 2);
  bf16* WpT   = (bf16*)alloc((size_t)768 * 768 * 2);
  bf16* W1T   = (bf16*)alloc((size_t)3072 * 768 * 2);
  bf16* W2T   = (bf16*)alloc((size_t)768 * 3072 * 2);
  char* R1 = (char*)alloc((size_t)16384 * 768 * 2);
  char* R2 = (char*)alloc((size_t)16384 * 3072 * 2);
  bf16* h   = (bf16*)R1;
  bf16* yb  = (bf16*)R1;
  bf16* h2  = (bf16*)R1;
  bf16* qkv = (bf16*)R2;
  bf16* m1  = (bf16*)R2;
  float* x2 = out;

  transpose_cast<<<dim3(36, 12), dim3(256), 0, stream>>>(Wqkv, WqkvT, 768, 2304);
  transpose_cast<<<dim3(12, 12), dim3(256), 0, stream>>>(Wp,   WpT,   768, 768);
  transpose_cast<<<dim3(48, 12), dim3(256), 0, stream>>>(W1,   W1T,   768, 3072);
  transpose_cast<<<dim3(12, 48), dim3(256), 0, stream>>>(W2,   W2T,   3072, 768);

  // LN1: x -> h (bf16)
  ln_kernel<<<dim3(16384), dim3(256), 0, stream>>>(x, g1, b1, h);
  // QKV: grid 64x9=576
  gemm256<0><<<dim3(576), dim3(512), 131072, stream>>>(h, WqkvT, nullptr, nullptr,
                                                       (void*)qkv, 16384, 2304, 768);
  // attention
  attn_kernel<<<dim3(3072), dim3(256), 0, stream>>>(qkv, yb);
  // proj + bias + residual(x) -> x2 (f32, in d_out); grid 64x3=192
  gemm256<2><<<dim3(192), dim3(512), 131072, stream>>>(yb, WpT, bp, x,
                                                       (void*)x2, 16384, 768, 768);
  // LN2
  ln_kernel<<<dim3(16384), dim3(256), 0, stream>>>(x2, g2, b2, h2);
  // MLP1 + bias + exact gelu; grid 64x12=768
  gemm256<1><<<dim3(768), dim3(512), 131072, stream>>>(h2, W1T, bm1, nullptr,
                                                       (void*)m1, 16384, 3072, 768);
  // MLP2 + bias + residual(x2) -> out; grid 64x3=192
  gemm256<2><<<dim3(192), dim3(512), 131072, stream>>>(m1, W2T, bm2, x2,
                                                       (void*)out, 16384, 768, 3072);
}